// Round 9
// baseline (111.964 us; speedup 1.0000x reference)
//
#include <hip/hip_runtime.h>

#define S_LEN 4096
#define D_MODEL 256
#define NH 4
#define DH 64
#define CSC 0.18033688011112042f   // log2(e) / sqrt(64)
#define FRAG 520                   // ushorts per fragment slot (512 + 8 pad)

typedef __attribute__((ext_vector_type(8))) short bf16x8;
typedef __attribute__((ext_vector_type(8))) unsigned short u16x8;
typedef __attribute__((ext_vector_type(4))) float f32x4;
typedef __attribute__((ext_vector_type(16))) float f32x16;
typedef __attribute__((ext_vector_type(2))) unsigned int u32x2;
typedef __attribute__((ext_vector_type(4))) unsigned int u32x4;

#define MFMA16(a, b, c) __builtin_amdgcn_mfma_f32_16x16x32_bf16((a), (b), (c), 0, 0, 0)
#define MFMA32(a, b, c) __builtin_amdgcn_mfma_f32_32x32x16_bf16((a), (b), (c), 0, 0, 0)

static __device__ __forceinline__ unsigned short f2bf(float f) {
  unsigned int u = __float_as_uint(f);
  u += 0x7fffu + ((u >> 16) & 1u);   // RTNE
  return (unsigned short)(u >> 16);
}

static __device__ __forceinline__ unsigned int cvtpk(float lo, float hi) {
  unsigned int r;
  asm("v_cvt_pk_bf16_f32 %0, %1, %2" : "=v"(r) : "v"(lo), "v"(hi));
  return r;   // lo -> [15:0], hi -> [31:16], RTNE
}

static __device__ __forceinline__ u16x8 cvt8(float4 a, float4 b) {
  u16x8 v;
  v[0] = f2bf(a.x); v[1] = f2bf(a.y); v[2] = f2bf(a.z); v[3] = f2bf(a.w);
  v[4] = f2bf(b.x); v[5] = f2bf(b.y); v[6] = f2bf(b.z); v[7] = f2bf(b.w);
  return v;
}

// P(f32 C-layout, two 32-row t-tiles) -> 4 bf16 B-operand fragments
static __device__ __forceinline__ void pack_pb(const f32x16& s0, const f32x16& s1,
                                               bf16x8* pb) {
  unsigned int u0[8], u1[8];
#pragma unroll
  for (int gg = 0; gg < 4; ++gg) {
    u0[gg * 2 + 0] = cvtpk(s0[4 * gg + 0], s0[4 * gg + 1]);
    u0[gg * 2 + 1] = cvtpk(s0[4 * gg + 2], s0[4 * gg + 3]);
    u1[gg * 2 + 0] = cvtpk(s1[4 * gg + 0], s1[4 * gg + 1]);
    u1[gg * 2 + 1] = cvtpk(s1[4 * gg + 2], s1[4 * gg + 3]);
  }
#pragma unroll
  for (int S = 0; S < 2; ++S) {
    u32x2 w0 = __builtin_amdgcn_permlane32_swap(u0[4 * S + 0], u0[4 * S + 2], false, false);
    u32x2 w1 = __builtin_amdgcn_permlane32_swap(u0[4 * S + 1], u0[4 * S + 3], false, false);
    u32x4 t0; t0[0] = w0[0]; t0[1] = w1[0]; t0[2] = w0[1]; t0[3] = w1[1];
    pb[S] = __builtin_bit_cast(bf16x8, t0);
    u32x2 w2 = __builtin_amdgcn_permlane32_swap(u1[4 * S + 0], u1[4 * S + 2], false, false);
    u32x2 w3 = __builtin_amdgcn_permlane32_swap(u1[4 * S + 1], u1[4 * S + 3], false, false);
    u32x4 t1; t1[0] = w2[0]; t1[1] = w3[0]; t1[2] = w2[1]; t1[3] = w3[1];
    pb[2 + S] = __builtin_bit_cast(bf16x8, t1);
  }
}

// ---------------------------------------------------------------------------
// Kernel 0: convert W{q,k,v} to bf16 in MFMA-B-fragment order (16x16x32).
// ---------------------------------------------------------------------------
__global__ __launch_bounds__(256) void prep(
    const float* __restrict__ Wq, const float* __restrict__ Wk,
    const float* __restrict__ Wv, unsigned short* __restrict__ Wb)
{
  const int gid = blockIdx.x * 256 + threadIdx.x;
  const int l   = gid & 63;
  const int f   = gid >> 6;
  const int kk  = f & 7;
  const int ctn = f >> 3;
  const int ct  = ctn & 3, nt = ctn >> 2;
  const int pj  = nt >> 2, h = nt & 3;
  const float* Wsel = (pj == 0) ? Wq : (pj == 1) ? Wk : Wv;
  const float* src =
      Wsel + (size_t)(h * 64 + ct * 16 + (l & 15)) * D_MODEL + kk * 32 + (l >> 4) * 8;
  float4 a = *(const float4*)src;
  float4 b = *(const float4*)(src + 4);
  *(u16x8*)(Wb + (size_t)gid * 8) = cvt8(a, b);
}

// ---------------------------------------------------------------------------
// Kernel 1: QKV projection with block-transpose coalesced stores.
// Q pre-scaled by CSC; V written transposed Vt[bh][d][s].
// ---------------------------------------------------------------------------
__global__ __launch_bounds__(256) void qkv_proj(
    const float* __restrict__ x, const unsigned short* __restrict__ Wb,
    const float* __restrict__ bq, const float* __restrict__ bk,
    const float* __restrict__ bv,
    unsigned short* __restrict__ Qh, unsigned short* __restrict__ Kh,
    unsigned short* __restrict__ Vt)
{
  __shared__ unsigned short xs[32][264];
  __shared__ float tbuf[32][68];          // block transpose buffer

  const int tid  = threadIdx.x;
  const int lane = tid & 63;
  const int w    = tid >> 6;
  const int r16  = lane & 15;
  const int hi   = lane >> 4;
  const int m0   = (blockIdx.x >> 1) * 32;
  const int ntB  = (blockIdx.x & 1) * 6;

  {  // stage x tile: 32 rows x 256 f32 -> bf16
    const int r  = tid >> 3;
    const int c0 = (tid & 7) * 32;
    const float* xp = x + (size_t)(m0 + r) * D_MODEL + c0;
#pragma unroll
    for (int i = 0; i < 32; i += 8) {
      float4 a = *(const float4*)(xp + i);
      float4 b = *(const float4*)(xp + i + 4);
      *(u16x8*)&xs[r][c0 + i] = cvt8(a, b);
    }
  }
  __syncthreads();

  const int bb = m0 >> 12;
  const int s_base = m0 & 4095;

  for (int t = 0; t < 6; ++t) {
    const int nt = ntB + t, pj = nt >> 2, h = nt & 3;
    f32x4 acc[2] = {};
    const size_t fb = (size_t)(nt * 4 + w) * 8;
#pragma unroll
    for (int kk = 0; kk < 8; ++kk) {
      bf16x8 bw = *(const bf16x8*)(Wb + (fb + kk) * 512 + lane * 8);
#pragma unroll
      for (int rt = 0; rt < 2; ++rt) {
        bf16x8 af = *(const bf16x8*)&xs[rt * 16 + r16][kk * 32 + hi * 8];
        acc[rt] = MFMA16(af, bw, acc[rt]);
      }
    }
    const float* bsel = (pj == 0) ? bq : (pj == 1) ? bk : bv;
    const float bias = bsel[h * 64 + w * 16 + r16];
    const float scl  = (pj == 0) ? CSC : 1.0f;

    // scatter into f32 transpose buffer [s_local][e_local]
#pragma unroll
    for (int rt = 0; rt < 2; ++rt)
#pragma unroll
      for (int j = 0; j < 4; ++j)
        tbuf[rt * 16 + hi * 4 + j][w * 16 + r16] = (acc[rt][j] + bias) * scl;
    __syncthreads();

    if (pj < 2) {   // coalesced 128B-row stores: thread -> (s_l, 8 cols)
      const int s_l = tid >> 3, c0 = (tid & 7) * 8;
      float4 a = *(const float4*)&tbuf[s_l][c0];
      float4 b = *(const float4*)&tbuf[s_l][c0 + 4];
      unsigned short* dst = ((pj == 0) ? Qh : Kh) +
          ((size_t)(bb * NH + h) * S_LEN + s_base + s_l) * DH + c0;
      *(u16x8*)dst = cvt8(a, b);
    } else {        // V transposed: thread -> (d_l, 8 s)
      const int d_l = tid & 63, sblk = (tid >> 6) * 8;
      u16x8 vv;
#pragma unroll
      for (int e = 0; e < 8; ++e) vv[e] = f2bf(tbuf[sblk + e][d_l]);
      unsigned short* dst = Vt +
          ((size_t)(bb * NH + h) * DH + d_l) * S_LEN + s_base + sblk;
      *(u16x8*)dst = vv;
    }
    __syncthreads();
  }
}

// ---------------------------------------------------------------------------
// Kernel 2: attention. 256 blocks (bh = bid&7 per XCD; 32 q-tiles of 128),
// 512 threads = 8 waves = 4 KV-groups x 2 q-waves; Q=64 rows per wave.
// Fragment-linear LDS (frag stride 1040B): conflict-free ds_read_b128.
// Sequenced per-q-tile softmax keeps <=2 s-tiles live (VGPR budget ~240:
// R8's (512,2) cap at 128 caused a 100-reg spill, WRITE_SIZE 110MB).
// ---------------------------------------------------------------------------
__global__ __launch_bounds__(512) void attn(
    const unsigned short* __restrict__ Qh,
    const unsigned short* __restrict__ Kh,
    const unsigned short* __restrict__ Vt,
    float* __restrict__ out)
{
  __shared__ unsigned short KV[2][2][4][8 * FRAG];  // [parity][K/V][grp][frag slots]

  const int tid = threadIdx.x;
  const int ln  = tid & 63;
  const int wv  = tid >> 6;        // 0..7
  const int g   = wv >> 1;         // KV group 0..3 (chunks ≡ g mod 4)
  const int qw  = wv & 1;          // q sub-tile
  const int r32 = ln & 31;
  const int h   = ln >> 5;

  const int bid = blockIdx.x;
  const int bh  = bid & 7;
  const int q0  = (bid >> 3) * 128;

  const unsigned short* Qb = Qh + (size_t)bh * S_LEN * DH;
  const unsigned short* Kb = Kh + (size_t)bh * S_LEN * DH;
  const unsigned short* Vb = Vt + (size_t)bh * DH * S_LEN;

  // Q fragments for 2 q-tiles: lane holds Q[q][d = s*16 + h*8 + j]
  bf16x8 qf[2][4];
#pragma unroll
  for (int qt = 0; qt < 2; ++qt) {
    const int q = q0 + qw * 64 + qt * 32 + r32;
#pragma unroll
    for (int s = 0; s < 4; ++s)
      qf[qt][s] = *(const bf16x8*)(Qb + (size_t)q * DH + s * 16 + h * 8);
  }

  f32x16 o[2][2] = {};        // [q-tile][d-tile]  (accumulators -> AGPRs)
  float l_run[2] = {0.f, 0.f};

  // ---- staging: 128 threads per group; coalesced read, frag-scatter write ----
  const int v   = tid & 127;
  const int gs  = tid >> 7;        // staging group == own wave's g
  const int sr  = v >> 1;          // row 0..63 (t for K, d for V^T)
  const int sc  = (v & 1) * 32;    // 32-ushort half
  int off[4];
#pragma unroll
  for (int m = 0; m < 4; ++m) {
    const int d0 = sc + 8 * m;
    const int f  = (d0 >> 4) * 2 + (sr >> 5);
    const int la = (sr & 31) + 32 * ((d0 >> 3) & 1);
    off[m] = f * FRAG + la * 8;
  }

  uint4 kst[4], vst[4];
#define LOAD_CHUNK(c)                                                          \
  { const uint4* kp = (const uint4*)(Kb + ((size_t)(c) * 64 + sr) * DH + sc);  \
    kst[0] = kp[0]; kst[1] = kp[1]; kst[2] = kp[2]; kst[3] = kp[3];            \
    const uint4* vp = (const uint4*)(Vb + (size_t)sr * S_LEN + (c) * 64 + sc); \
    vst[0] = vp[0]; vst[1] = vp[1]; vst[2] = vp[2]; vst[3] = vp[3]; }
#define STAGE(par)                                                             \
  { _Pragma("unroll")                                                          \
    for (int m = 0; m < 4; ++m) {                                              \
      *(uint4*)&KV[par][0][gs][off[m]] = kst[m];                               \
      *(uint4*)&KV[par][1][gs][off[m]] = vst[m];                               \
    } }

  LOAD_CHUNK(gs);
  STAGE(0);
  LOAD_CHUNK(4 + gs);

  for (int it = 0; it < 16; ++it) {
    __syncthreads();
    if (it < 15) {
      STAGE((it + 1) & 1);
      int c = 4 * (it + 2) + gs;  if (c > 63) c = 63;
      LOAD_CHUNK(c);
    }
    const unsigned short* Kc = &KV[it & 1][0][g][0];
    const unsigned short* Vc = &KV[it & 1][1][g][0];
    const int lb = ln * 8;

    // ---- K fragments once; shared by both q-tiles ----
    bf16x8 ka[8];
#pragma unroll
    for (int s = 0; s < 8; ++s)
      ka[s] = *(const bf16x8*)(Kc + lb + s * FRAG);

    bf16x8 pb0[4], pb1[4];
    {  // ---- q-tile 0: QK^T -> exp2 -> pack (frees s-tiles before tile 1) ----
      f32x16 s00 = {}, s01 = {};
      __builtin_amdgcn_s_setprio(1);
#pragma unroll
      for (int s = 0; s < 4; ++s) {
        s00 = MFMA32(ka[2 * s + 0], qf[0][s], s00);
        s01 = MFMA32(ka[2 * s + 1], qf[0][s], s01);
      }
      __builtin_amdgcn_s_setprio(0);
      float ps = 0.f;
#pragma unroll
      for (int i = 0; i < 16; ++i) {
        s00[i] = __builtin_amdgcn_exp2f(s00[i]);  ps += s00[i];
        s01[i] = __builtin_amdgcn_exp2f(s01[i]);  ps += s01[i];
      }
      l_run[0] += ps;
      pack_pb(s00, s01, pb0);
    }
    {  // ---- q-tile 1 ----
      f32x16 s10 = {}, s11 = {};
      __builtin_amdgcn_s_setprio(1);
#pragma unroll
      for (int s = 0; s < 4; ++s) {
        s10 = MFMA32(ka[2 * s + 0], qf[1][s], s10);
        s11 = MFMA32(ka[2 * s + 1], qf[1][s], s11);
      }
      __builtin_amdgcn_s_setprio(0);
      float ps = 0.f;
#pragma unroll
      for (int i = 0; i < 16; ++i) {
        s10[i] = __builtin_amdgcn_exp2f(s10[i]);  ps += s10[i];
        s11[i] = __builtin_amdgcn_exp2f(s11[i]);  ps += s11[i];
      }
      l_run[1] += ps;
      pack_pb(s10, s11, pb1);
    }

    // ---- PV: V frags loaded after K frags dead; shared across q-tiles ----
    __builtin_amdgcn_s_setprio(1);
#pragma unroll
    for (int s = 0; s < 4; ++s) {
      bf16x8 b0 = *(const bf16x8*)(Vc + lb + (s * 2 + 0) * FRAG);
      bf16x8 b1 = *(const bf16x8*)(Vc + lb + (s * 2 + 1) * FRAG);
      o[0][0] = MFMA32(b0, pb0[s], o[0][0]);
      o[0][1] = MFMA32(b1, pb0[s], o[0][1]);
      o[1][0] = MFMA32(b0, pb1[s], o[1][0]);
      o[1][1] = MFMA32(b1, pb1[s], o[1][1]);
    }
    __builtin_amdgcn_s_setprio(0);
  }

  // ---- combine 4 -> 2 -> 1 (exact: partials additive) ----
  __syncthreads();
  float* cb = (float*)&KV[0][0][0][0];

  if (wv >= 4) {                       // round 1 publish: wv-4 absorbs
    const int base = ((wv - 4) * 64 + ln) * 68;
#pragma unroll
    for (int i = 0; i < 16; ++i) {
      cb[base + i]      = o[0][0][i];  cb[base + 16 + i] = o[0][1][i];
      cb[base + 32 + i] = o[1][0][i];  cb[base + 48 + i] = o[1][1][i];
    }
    cb[base + 64] = l_run[0];  cb[base + 65] = l_run[1];
  }
  __syncthreads();
  if (wv < 4) {
    const int base = (wv * 64 + ln) * 68;
#pragma unroll
    for (int i = 0; i < 16; ++i) {
      o[0][0][i] += cb[base + i];       o[0][1][i] += cb[base + 16 + i];
      o[1][0][i] += cb[base + 32 + i];  o[1][1][i] += cb[base + 48 + i];
    }
    l_run[0] += cb[base + 64];  l_run[1] += cb[base + 65];
  }
  __syncthreads();
  if (wv == 2 || wv == 3) {            // round 2 publish: wv-2 absorbs
    const int base = ((wv - 2) * 64 + ln) * 68;
#pragma unroll
    for (int i = 0; i < 16; ++i) {
      cb[base + i]      = o[0][0][i];  cb[base + 16 + i] = o[0][1][i];
      cb[base + 32 + i] = o[1][0][i];  cb[base + 48 + i] = o[1][1][i];
    }
    cb[base + 64] = l_run[0];  cb[base + 65] = l_run[1];
  }
  __syncthreads();
  if (wv < 2) {
    const int base = (wv * 64 + ln) * 68;
#pragma unroll
    for (int i = 0; i < 16; ++i) {
      o[0][0][i] += cb[base + i];       o[0][1][i] += cb[base + 16 + i];
      o[1][0][i] += cb[base + 32 + i];  o[1][1][i] += cb[base + 48 + i];
    }
    l_run[0] += cb[base + 64];  l_run[1] += cb[base + 65];

    // ---- epilogue: l across h-halves, normalize, store ----
    const int bb = bh >> 2, hd = bh & 3;
#pragma unroll
    for (int qt = 0; qt < 2; ++qt) {
      const float lt  = l_run[qt] + __shfl_xor(l_run[qt], 32);
      const float inv = 1.f / lt;
      const int q = q0 + wv * 64 + qt * 32 + r32;
      float* op = out + ((size_t)(bb * S_LEN + q)) * D_MODEL + hd * DH;
#pragma unroll
      for (int gg = 0; gg < 4; ++gg) {
        float4 v0, v1;
        v0.x = o[qt][0][4 * gg + 0] * inv;  v0.y = o[qt][0][4 * gg + 1] * inv;
        v0.z = o[qt][0][4 * gg + 2] * inv;  v0.w = o[qt][0][4 * gg + 3] * inv;
        *(float4*)(op + 8 * gg + 4 * h) = v0;
        v1.x = o[qt][1][4 * gg + 0] * inv;  v1.y = o[qt][1][4 * gg + 1] * inv;
        v1.z = o[qt][1][4 * gg + 2] * inv;  v1.w = o[qt][1][4 * gg + 3] * inv;
        *(float4*)(op + 32 + 8 * gg + 4 * h) = v1;
      }
    }
  }
}

// ---------------------------------------------------------------------------
extern "C" void kernel_launch(void* const* d_in, const int* in_sizes, int n_in,
                              void* d_out, int out_size, void* d_ws, size_t ws_size,
                              hipStream_t stream) {
  const float* x  = (const float*)d_in[0];
  const float* Wq = (const float*)d_in[1];
  const float* bq = (const float*)d_in[2];
  const float* Wk = (const float*)d_in[3];
  const float* bk = (const float*)d_in[4];
  const float* Wv = (const float*)d_in[5];
  const float* bv = (const float*)d_in[6];
  float* out = (float*)d_out;

  const size_t per = (size_t)2 * NH * S_LEN * DH;       // 2M bf16 elems each
  if (ws_size < 3 * per * sizeof(unsigned short)) return;
  unsigned short* Qh = (unsigned short*)d_ws;
  unsigned short* Kh = Qh + per;
  unsigned short* Vt = Kh + per;
  unsigned short* Wb = (unsigned short*)d_out;   // scratch; attn overwrites out

  prep<<<96, 256, 0, stream>>>(Wq, Wk, Wv, Wb);
  qkv_proj<<<512, 256, 0, stream>>>(x, Wb, bq, bk, bv, Qh, Kh, Vt);
  attn<<<256, 512, 0, stream>>>(Qh, Kh, Vt, out);
}

// Round 10
// 100.117 us; speedup vs baseline: 1.1183x; 1.1183x over previous
//
#include <hip/hip_runtime.h>

#define S_LEN 4096
#define D_MODEL 256
#define NH 4
#define DH 64
#define CSC 0.18033688011112042f   // log2(e) / sqrt(64)
#define FRAG 520                   // ushorts per fragment slot (512 + 8 pad)

typedef __attribute__((ext_vector_type(8))) short bf16x8;
typedef __attribute__((ext_vector_type(8))) unsigned short u16x8;
typedef __attribute__((ext_vector_type(4))) float f32x4;
typedef __attribute__((ext_vector_type(16))) float f32x16;
typedef __attribute__((ext_vector_type(2))) unsigned int u32x2;
typedef __attribute__((ext_vector_type(4))) unsigned int u32x4;

#define MFMA16(a, b, c) __builtin_amdgcn_mfma_f32_16x16x32_bf16((a), (b), (c), 0, 0, 0)
#define MFMA32(a, b, c) __builtin_amdgcn_mfma_f32_32x32x16_bf16((a), (b), (c), 0, 0, 0)

static __device__ __forceinline__ unsigned short f2bf(float f) {
  unsigned int u = __float_as_uint(f);
  u += 0x7fffu + ((u >> 16) & 1u);   // RTNE
  return (unsigned short)(u >> 16);
}

static __device__ __forceinline__ unsigned int cvtpk(float lo, float hi) {
  unsigned int r;
  asm("v_cvt_pk_bf16_f32 %0, %1, %2" : "=v"(r) : "v"(lo), "v"(hi));
  return r;   // lo -> [15:0], hi -> [31:16], RTNE
}

static __device__ __forceinline__ u16x8 cvt8(float4 a, float4 b) {
  u16x8 v;
  v[0] = f2bf(a.x); v[1] = f2bf(a.y); v[2] = f2bf(a.z); v[3] = f2bf(a.w);
  v[4] = f2bf(b.x); v[5] = f2bf(b.y); v[6] = f2bf(b.z); v[7] = f2bf(b.w);
  return v;
}

// P(f32 C-layout, two 32-row t-tiles) -> 4 bf16 B-operand fragments
static __device__ __forceinline__ void pack_pb(const f32x16& s0, const f32x16& s1,
                                               bf16x8* pb) {
  unsigned int u0[8], u1[8];
#pragma unroll
  for (int gg = 0; gg < 4; ++gg) {
    u0[gg * 2 + 0] = cvtpk(s0[4 * gg + 0], s0[4 * gg + 1]);
    u0[gg * 2 + 1] = cvtpk(s0[4 * gg + 2], s0[4 * gg + 3]);
    u1[gg * 2 + 0] = cvtpk(s1[4 * gg + 0], s1[4 * gg + 1]);
    u1[gg * 2 + 1] = cvtpk(s1[4 * gg + 2], s1[4 * gg + 3]);
  }
#pragma unroll
  for (int S = 0; S < 2; ++S) {
    u32x2 w0 = __builtin_amdgcn_permlane32_swap(u0[4 * S + 0], u0[4 * S + 2], false, false);
    u32x2 w1 = __builtin_amdgcn_permlane32_swap(u0[4 * S + 1], u0[4 * S + 3], false, false);
    u32x4 t0; t0[0] = w0[0]; t0[1] = w1[0]; t0[2] = w0[1]; t0[3] = w1[1];
    pb[S] = __builtin_bit_cast(bf16x8, t0);
    u32x2 w2 = __builtin_amdgcn_permlane32_swap(u1[4 * S + 0], u1[4 * S + 2], false, false);
    u32x2 w3 = __builtin_amdgcn_permlane32_swap(u1[4 * S + 1], u1[4 * S + 3], false, false);
    u32x4 t1; t1[0] = w2[0]; t1[1] = w3[0]; t1[2] = w2[1]; t1[3] = w3[1];
    pb[2 + S] = __builtin_bit_cast(bf16x8, t1);
  }
}

// ---------------------------------------------------------------------------
// Kernel 0: convert W{q,k,v} to bf16 in MFMA-B-fragment order (16x16x32).
// ---------------------------------------------------------------------------
__global__ __launch_bounds__(256) void prep(
    const float* __restrict__ Wq, const float* __restrict__ Wk,
    const float* __restrict__ Wv, unsigned short* __restrict__ Wb)
{
  const int gid = blockIdx.x * 256 + threadIdx.x;
  const int l   = gid & 63;
  const int f   = gid >> 6;
  const int kk  = f & 7;
  const int ctn = f >> 3;
  const int ct  = ctn & 3, nt = ctn >> 2;
  const int pj  = nt >> 2, h = nt & 3;
  const float* Wsel = (pj == 0) ? Wq : (pj == 1) ? Wk : Wv;
  const float* src =
      Wsel + (size_t)(h * 64 + ct * 16 + (l & 15)) * D_MODEL + kk * 32 + (l >> 4) * 8;
  float4 a = *(const float4*)src;
  float4 b = *(const float4*)(src + 4);
  *(u16x8*)(Wb + (size_t)gid * 8) = cvt8(a, b);
}

// ---------------------------------------------------------------------------
// Kernel 1: QKV projection with block-transpose coalesced stores.
// Q pre-scaled by CSC; V written transposed Vt[bh][d][s].
// ---------------------------------------------------------------------------
__global__ __launch_bounds__(256) void qkv_proj(
    const float* __restrict__ x, const unsigned short* __restrict__ Wb,
    const float* __restrict__ bq, const float* __restrict__ bk,
    const float* __restrict__ bv,
    unsigned short* __restrict__ Qh, unsigned short* __restrict__ Kh,
    unsigned short* __restrict__ Vt)
{
  __shared__ unsigned short xs[32][264];
  __shared__ float tbuf[32][68];          // block transpose buffer

  const int tid  = threadIdx.x;
  const int lane = tid & 63;
  const int w    = tid >> 6;
  const int r16  = lane & 15;
  const int hi   = lane >> 4;
  const int m0   = (blockIdx.x >> 1) * 32;
  const int ntB  = (blockIdx.x & 1) * 6;

  {  // stage x tile: 32 rows x 256 f32 -> bf16
    const int r  = tid >> 3;
    const int c0 = (tid & 7) * 32;
    const float* xp = x + (size_t)(m0 + r) * D_MODEL + c0;
#pragma unroll
    for (int i = 0; i < 32; i += 8) {
      float4 a = *(const float4*)(xp + i);
      float4 b = *(const float4*)(xp + i + 4);
      *(u16x8*)&xs[r][c0 + i] = cvt8(a, b);
    }
  }
  __syncthreads();

  const int bb = m0 >> 12;
  const int s_base = m0 & 4095;

  for (int t = 0; t < 6; ++t) {
    const int nt = ntB + t, pj = nt >> 2, h = nt & 3;
    f32x4 acc[2] = {};
    const size_t fb = (size_t)(nt * 4 + w) * 8;
#pragma unroll
    for (int kk = 0; kk < 8; ++kk) {
      bf16x8 bw = *(const bf16x8*)(Wb + (fb + kk) * 512 + lane * 8);
#pragma unroll
      for (int rt = 0; rt < 2; ++rt) {
        bf16x8 af = *(const bf16x8*)&xs[rt * 16 + r16][kk * 32 + hi * 8];
        acc[rt] = MFMA16(af, bw, acc[rt]);
      }
    }
    const float* bsel = (pj == 0) ? bq : (pj == 1) ? bk : bv;
    const float bias = bsel[h * 64 + w * 16 + r16];
    const float scl  = (pj == 0) ? CSC : 1.0f;

    // scatter into f32 transpose buffer [s_local][e_local]
#pragma unroll
    for (int rt = 0; rt < 2; ++rt)
#pragma unroll
      for (int j = 0; j < 4; ++j)
        tbuf[rt * 16 + hi * 4 + j][w * 16 + r16] = (acc[rt][j] + bias) * scl;
    __syncthreads();

    if (pj < 2) {   // coalesced 128B-row stores: thread -> (s_l, 8 cols)
      const int s_l = tid >> 3, c0 = (tid & 7) * 8;
      float4 a = *(const float4*)&tbuf[s_l][c0];
      float4 b = *(const float4*)&tbuf[s_l][c0 + 4];
      unsigned short* dst = ((pj == 0) ? Qh : Kh) +
          ((size_t)(bb * NH + h) * S_LEN + s_base + s_l) * DH + c0;
      *(u16x8*)dst = cvt8(a, b);
    } else {        // V transposed: thread -> (d_l, 8 s)
      const int d_l = tid & 63, sblk = (tid >> 6) * 8;
      u16x8 vv;
#pragma unroll
      for (int e = 0; e < 8; ++e) vv[e] = f2bf(tbuf[sblk + e][d_l]);
      unsigned short* dst = Vt +
          ((size_t)(bb * NH + h) * DH + d_l) * S_LEN + s_base + sblk;
      *(u16x8*)dst = vv;
    }
    __syncthreads();
  }
}

// ---------------------------------------------------------------------------
// Kernel 2: attention = R7 structure + frag-linear LDS.
// grid = 256 (bh = bid&7 per XCD; 32 q-tiles of 128), block = 1024 = 16 waves:
// KV-split 4 (group g = wave>>2, chunks ≡ g mod 4) x 4 q-waves, Q=32/wave.
// LDS 130KB: [parity][K/V][grp][8 frags x FRAG]; frag-linear reads
// (base + lane*16 + f*1040B, conflict-free, offsets fold to immediates).
// No-max softmax; P in registers; combine 4->2->1. VGPR ~64-90 (no spill;
// R8/R9's Q=64 needed ~240 and spilled at the compiler's 128 budget).
// ---------------------------------------------------------------------------
__global__ __launch_bounds__(1024) void attn(
    const unsigned short* __restrict__ Qh,
    const unsigned short* __restrict__ Kh,
    const unsigned short* __restrict__ Vt,
    float* __restrict__ out)
{
  __shared__ unsigned short KV[2][2][4][8 * FRAG];  // [parity][K/V][grp][slots]

  const int tid = threadIdx.x;
  const int ln  = tid & 63;
  const int wv  = tid >> 6;       // 0..15
  const int g   = wv >> 2;        // KV group 0..3
  const int wq  = wv & 3;         // q sub-tile
  const int r32 = ln & 31;
  const int h   = ln >> 5;

  const int bid = blockIdx.x;
  const int bh  = bid & 7;                 // XCD-local bh
  const int q0  = (bid >> 3) * 128;

  const unsigned short* Qb = Qh + (size_t)bh * S_LEN * DH;
  const unsigned short* Kb = Kh + (size_t)bh * S_LEN * DH;
  const unsigned short* Vb = Vt + (size_t)bh * DH * S_LEN;

  // Q as B-operand of swapped QK: lane holds Q[q=r32][d = s*16 + h*8 + j]
  const int q = q0 + wq * 32 + r32;
  bf16x8 qf[4];
#pragma unroll
  for (int s = 0; s < 4; ++s)
    qf[s] = *(const bf16x8*)(Qb + (size_t)q * DH + s * 16 + h * 8);

  f32x16 o0 = {}, o1 = {};     // o^T: col=q, rows=d (two 32-d tiles)
  float l_run = 0.f;

  // ---- staging: 256 threads per group; coalesced read, frag-scatter write ----
  const int u  = tid & 255;
  const int gs = tid >> 8;         // staging group == own wave's g
  const int sr = u >> 2;           // row 0..63 (t for K, d for V^T)
  const int sc = (u & 3) * 16;     // ushort col
  int off[2];
#pragma unroll
  for (int m = 0; m < 2; ++m) {
    const int d0 = sc + 8 * m;
    const int f  = (d0 >> 4) * 2 + (sr >> 5);
    const int la = (sr & 31) + 32 * ((d0 >> 3) & 1);
    off[m] = f * FRAG + la * 8;
  }

  uint4 kst[2], vst[2];
#define LOAD_CHUNK(c)                                                            \
  { const unsigned short* kp = Kb + ((size_t)(c) * 64 + sr) * DH + sc;           \
    kst[0] = *(const uint4*)kp;  kst[1] = *(const uint4*)(kp + 8);               \
    const unsigned short* vp = Vb + (size_t)sr * S_LEN + (c) * 64 + sc;          \
    vst[0] = *(const uint4*)vp;  vst[1] = *(const uint4*)(vp + 8); }
#define STAGE(par)                                                               \
  { _Pragma("unroll")                                                            \
    for (int m = 0; m < 2; ++m) {                                                \
      *(uint4*)&KV[par][0][gs][off[m]] = kst[m];                                 \
      *(uint4*)&KV[par][1][gs][off[m]] = vst[m];                                 \
    } }

  LOAD_CHUNK(gs);
  STAGE(0);
  LOAD_CHUNK(4 + gs);

  for (int it = 0; it < 16; ++it) {
    __syncthreads();   // parity-(it&1) writes visible; prior same-parity reads done
    if (it < 15) {     // stage chunk for it+1 into the other parity buffer
      STAGE((it + 1) & 1);
      int c = 4 * (it + 2) + gs;  if (c > 63) c = 63;   // prefetch for it+2
      LOAD_CHUNK(c);
    }
    const unsigned short* Kc = &KV[it & 1][0][g][0];
    const unsigned short* Vc = &KV[it & 1][1][g][0];
    const int lb = ln * 8;

    // ---- QK^T (swapped, 32x32x16): S^T[t][q], t-halves 0/1 ----
    f32x16 s0 = {}, s1 = {};
    __builtin_amdgcn_s_setprio(1);
#pragma unroll
    for (int s = 0; s < 4; ++s) {
      bf16x8 a0 = *(const bf16x8*)(Kc + lb + (2 * s + 0) * FRAG);
      bf16x8 a1 = *(const bf16x8*)(Kc + lb + (2 * s + 1) * FRAG);
      s0 = MFMA32(a0, qf[s], s0);
      s1 = MFMA32(a1, qf[s], s1);
    }
    __builtin_amdgcn_s_setprio(0);

    // ---- P = exp2(S^T) (no max-subtraction: logits provably bounded) ----
    float ps = 0.f;
#pragma unroll
    for (int i = 0; i < 16; ++i) {
      s0[i] = __builtin_amdgcn_exp2f(s0[i]);  ps += s0[i];
      s1[i] = __builtin_amdgcn_exp2f(s1[i]);  ps += s1[i];
    }
    l_run += ps;

    // ---- P(f32 C-layout) -> bf16 B-operand frags ----
    bf16x8 pb[4];
    pack_pb(s0, s1, pb);

    // ---- PV (swapped): o^T[d][q] += V^T[d][t] * P^T[t][q] ----
    __builtin_amdgcn_s_setprio(1);
#pragma unroll
    for (int s = 0; s < 4; ++s) {
      bf16x8 b0 = *(const bf16x8*)(Vc + lb + (2 * s + 0) * FRAG);
      bf16x8 b1 = *(const bf16x8*)(Vc + lb + (2 * s + 1) * FRAG);
      o0 = MFMA32(b0, pb[s], o0);
      o1 = MFMA32(b1, pb[s], o1);
    }
    __builtin_amdgcn_s_setprio(0);
  }

  // ---- KV-split combine: 4 -> 2 -> 1 (exact: partials additive) ----
  __syncthreads();                            // last computes done
  float* cb = (float*)&KV[0][0][0][0];        // scratch; rounds use <70KB
  const int cbase = wq * 64 + ln;             // 0..255

  // round 1: groups 2,3 publish; groups 0,1 absorb
  if (g >= 2) {
    const int base = ((g - 2) * 256 + cbase) * 33;
#pragma unroll
    for (int i = 0; i < 16; ++i) { cb[base + i] = o0[i]; cb[base + 16 + i] = o1[i]; }
    cb[base + 32] = l_run;
  }
  __syncthreads();
  if (g < 2) {
    const int base = (g * 256 + cbase) * 33;
#pragma unroll
    for (int i = 0; i < 16; ++i) { o0[i] += cb[base + i]; o1[i] += cb[base + 16 + i]; }
    l_run += cb[base + 32];
  }
  __syncthreads();
  // round 2: group 1 publishes; group 0 absorbs
  if (g == 1) {
    const int base = cbase * 33;
#pragma unroll
    for (int i = 0; i < 16; ++i) { cb[base + i] = o0[i]; cb[base + 16 + i] = o1[i]; }
    cb[base + 32] = l_run;
  }
  __syncthreads();
  if (g == 0) {
    const int base = cbase * 33;
#pragma unroll
    for (int i = 0; i < 16; ++i) { o0[i] += cb[base + i]; o1[i] += cb[base + 16 + i]; }
    l_run += cb[base + 32];

    // ---- epilogue: l across h-halves, normalize, store ----
    const float lt  = l_run + __shfl_xor(l_run, 32);
    const float inv = 1.f / lt;
    const int bb = bh >> 2, hd = bh & 3;
    float* op = out + ((size_t)(bb * S_LEN + q)) * D_MODEL + hd * DH;
#pragma unroll
    for (int gg = 0; gg < 4; ++gg) {
      float4 v0, v1;
      v0.x = o0[4 * gg + 0] * inv;  v0.y = o0[4 * gg + 1] * inv;
      v0.z = o0[4 * gg + 2] * inv;  v0.w = o0[4 * gg + 3] * inv;
      *(float4*)(op + 8 * gg + 4 * h) = v0;
      v1.x = o1[4 * gg + 0] * inv;  v1.y = o1[4 * gg + 1] * inv;
      v1.z = o1[4 * gg + 2] * inv;  v1.w = o1[4 * gg + 3] * inv;
      *(float4*)(op + 32 + 8 * gg + 4 * h) = v1;
    }
  }
}

// ---------------------------------------------------------------------------
extern "C" void kernel_launch(void* const* d_in, const int* in_sizes, int n_in,
                              void* d_out, int out_size, void* d_ws, size_t ws_size,
                              hipStream_t stream) {
  const float* x  = (const float*)d_in[0];
  const float* Wq = (const float*)d_in[1];
  const float* bq = (const float*)d_in[2];
  const float* Wk = (const float*)d_in[3];
  const float* bk = (const float*)d_in[4];
  const float* Wv = (const float*)d_in[5];
  const float* bv = (const float*)d_in[6];
  float* out = (float*)d_out;

  const size_t per = (size_t)2 * NH * S_LEN * DH;       // 2M bf16 elems each
  if (ws_size < 3 * per * sizeof(unsigned short)) return;
  unsigned short* Qh = (unsigned short*)d_ws;
  unsigned short* Kh = Qh + per;
  unsigned short* Vt = Kh + per;
  unsigned short* Wb = (unsigned short*)d_out;   // scratch; attn overwrites out

  prep<<<96, 256, 0, stream>>>(Wq, Wk, Wv, Wb);
  qkv_proj<<<512, 256, 0, stream>>>(x, Wb, bq, bk, bv, Qh, Kh, Vt);
  attn<<<256, 1024, 0, stream>>>(Qh, Kh, Vt, out);
}

// Round 11
// 66.731 us; speedup vs baseline: 1.6778x; 1.5003x over previous
//
#include <hip/hip_runtime.h>

#define S_LEN 4096
#define D_MODEL 256
#define NH 4
#define DH 64
#define CSC 0.18033688011112042f   // log2(e) / sqrt(64)
#define FRAG 520                   // ushorts per fragment slot (512 + 8 pad)

typedef __attribute__((ext_vector_type(8))) short bf16x8;
typedef __attribute__((ext_vector_type(8))) unsigned short u16x8;
typedef __attribute__((ext_vector_type(4))) float f32x4;
typedef __attribute__((ext_vector_type(16))) float f32x16;
typedef __attribute__((ext_vector_type(2))) unsigned int u32x2;
typedef __attribute__((ext_vector_type(4))) unsigned int u32x4;

#define MFMA16(a, b, c) __builtin_amdgcn_mfma_f32_16x16x32_bf16((a), (b), (c), 0, 0, 0)
#define MFMA32(a, b, c) __builtin_amdgcn_mfma_f32_32x32x16_bf16((a), (b), (c), 0, 0, 0)

static __device__ __forceinline__ unsigned short f2bf(float f) {
  unsigned int u = __float_as_uint(f);
  u += 0x7fffu + ((u >> 16) & 1u);   // RTNE
  return (unsigned short)(u >> 16);
}

static __device__ __forceinline__ unsigned int cvtpk(float lo, float hi) {
  unsigned int r;
  asm("v_cvt_pk_bf16_f32 %0, %1, %2" : "=v"(r) : "v"(lo), "v"(hi));
  return r;   // lo -> [15:0], hi -> [31:16], RTNE
}

static __device__ __forceinline__ u16x8 cvt8(float4 a, float4 b) {
  u16x8 v;
  v[0] = f2bf(a.x); v[1] = f2bf(a.y); v[2] = f2bf(a.z); v[3] = f2bf(a.w);
  v[4] = f2bf(b.x); v[5] = f2bf(b.y); v[6] = f2bf(b.z); v[7] = f2bf(b.w);
  return v;
}

// P(f32 C-layout, two 32-row t-tiles) -> 4 bf16 B-operand fragments
static __device__ __forceinline__ void pack_pb(const f32x16& s0, const f32x16& s1,
                                               bf16x8* pb) {
  unsigned int u0[8], u1[8];
#pragma unroll
  for (int gg = 0; gg < 4; ++gg) {
    u0[gg * 2 + 0] = cvtpk(s0[4 * gg + 0], s0[4 * gg + 1]);
    u0[gg * 2 + 1] = cvtpk(s0[4 * gg + 2], s0[4 * gg + 3]);
    u1[gg * 2 + 0] = cvtpk(s1[4 * gg + 0], s1[4 * gg + 1]);
    u1[gg * 2 + 1] = cvtpk(s1[4 * gg + 2], s1[4 * gg + 3]);
  }
#pragma unroll
  for (int S = 0; S < 2; ++S) {
    u32x2 w0 = __builtin_amdgcn_permlane32_swap(u0[4 * S + 0], u0[4 * S + 2], false, false);
    u32x2 w1 = __builtin_amdgcn_permlane32_swap(u0[4 * S + 1], u0[4 * S + 3], false, false);
    u32x4 t0; t0[0] = w0[0]; t0[1] = w1[0]; t0[2] = w0[1]; t0[3] = w1[1];
    pb[S] = __builtin_bit_cast(bf16x8, t0);
    u32x2 w2 = __builtin_amdgcn_permlane32_swap(u1[4 * S + 0], u1[4 * S + 2], false, false);
    u32x2 w3 = __builtin_amdgcn_permlane32_swap(u1[4 * S + 1], u1[4 * S + 3], false, false);
    u32x4 t1; t1[0] = w2[0]; t1[1] = w3[0]; t1[2] = w2[1]; t1[3] = w3[1];
    pb[2 + S] = __builtin_bit_cast(bf16x8, t1);
  }
}

// ---------------------------------------------------------------------------
// Kernel 0: convert W{q,k,v} to bf16 in MFMA-B-fragment order (16x16x32).
// ---------------------------------------------------------------------------
__global__ __launch_bounds__(256) void prep(
    const float* __restrict__ Wq, const float* __restrict__ Wk,
    const float* __restrict__ Wv, unsigned short* __restrict__ Wb)
{
  const int gid = blockIdx.x * 256 + threadIdx.x;
  const int l   = gid & 63;
  const int f   = gid >> 6;
  const int kk  = f & 7;
  const int ctn = f >> 3;
  const int ct  = ctn & 3, nt = ctn >> 2;
  const int pj  = nt >> 2, h = nt & 3;
  const float* Wsel = (pj == 0) ? Wq : (pj == 1) ? Wk : Wv;
  const float* src =
      Wsel + (size_t)(h * 64 + ct * 16 + (l & 15)) * D_MODEL + kk * 32 + (l >> 4) * 8;
  float4 a = *(const float4*)src;
  float4 b = *(const float4*)(src + 4);
  *(u16x8*)(Wb + (size_t)gid * 8) = cvt8(a, b);
}

// ---------------------------------------------------------------------------
// Kernel 1: QKV projection with block-transpose coalesced stores.
// Q pre-scaled by CSC; V written transposed Vt[bh][d][s].
// ---------------------------------------------------------------------------
__global__ __launch_bounds__(256) void qkv_proj(
    const float* __restrict__ x, const unsigned short* __restrict__ Wb,
    const float* __restrict__ bq, const float* __restrict__ bk,
    const float* __restrict__ bv,
    unsigned short* __restrict__ Qh, unsigned short* __restrict__ Kh,
    unsigned short* __restrict__ Vt)
{
  __shared__ unsigned short xs[32][264];
  __shared__ float tbuf[32][68];          // block transpose buffer

  const int tid  = threadIdx.x;
  const int lane = tid & 63;
  const int w    = tid >> 6;
  const int r16  = lane & 15;
  const int hi   = lane >> 4;
  const int m0   = (blockIdx.x >> 1) * 32;
  const int ntB  = (blockIdx.x & 1) * 6;

  {  // stage x tile: 32 rows x 256 f32 -> bf16
    const int r  = tid >> 3;
    const int c0 = (tid & 7) * 32;
    const float* xp = x + (size_t)(m0 + r) * D_MODEL + c0;
#pragma unroll
    for (int i = 0; i < 32; i += 8) {
      float4 a = *(const float4*)(xp + i);
      float4 b = *(const float4*)(xp + i + 4);
      *(u16x8*)&xs[r][c0 + i] = cvt8(a, b);
    }
  }
  __syncthreads();

  const int bb = m0 >> 12;
  const int s_base = m0 & 4095;

  for (int t = 0; t < 6; ++t) {
    const int nt = ntB + t, pj = nt >> 2, h = nt & 3;
    f32x4 acc[2] = {};
    const size_t fb = (size_t)(nt * 4 + w) * 8;
#pragma unroll
    for (int kk = 0; kk < 8; ++kk) {
      bf16x8 bw = *(const bf16x8*)(Wb + (fb + kk) * 512 + lane * 8);
#pragma unroll
      for (int rt = 0; rt < 2; ++rt) {
        bf16x8 af = *(const bf16x8*)&xs[rt * 16 + r16][kk * 32 + hi * 8];
        acc[rt] = MFMA16(af, bw, acc[rt]);
      }
    }
    const float* bsel = (pj == 0) ? bq : (pj == 1) ? bk : bv;
    const float bias = bsel[h * 64 + w * 16 + r16];
    const float scl  = (pj == 0) ? CSC : 1.0f;

    // scatter into f32 transpose buffer [s_local][e_local]
#pragma unroll
    for (int rt = 0; rt < 2; ++rt)
#pragma unroll
      for (int j = 0; j < 4; ++j)
        tbuf[rt * 16 + hi * 4 + j][w * 16 + r16] = (acc[rt][j] + bias) * scl;
    __syncthreads();

    if (pj < 2) {   // coalesced 128B-row stores: thread -> (s_l, 8 cols)
      const int s_l = tid >> 3, c0 = (tid & 7) * 8;
      float4 a = *(const float4*)&tbuf[s_l][c0];
      float4 b = *(const float4*)&tbuf[s_l][c0 + 4];
      unsigned short* dst = ((pj == 0) ? Qh : Kh) +
          ((size_t)(bb * NH + h) * S_LEN + s_base + s_l) * DH + c0;
      *(u16x8*)dst = cvt8(a, b);
    } else {        // V transposed: thread -> (d_l, 8 s)
      const int d_l = tid & 63, sblk = (tid >> 6) * 8;
      u16x8 vv;
#pragma unroll
      for (int e = 0; e < 8; ++e) vv[e] = f2bf(tbuf[sblk + e][d_l]);
      unsigned short* dst = Vt +
          ((size_t)(bb * NH + h) * DH + d_l) * S_LEN + s_base + sblk;
      *(u16x8*)dst = vv;
    }
    __syncthreads();
  }
}

// ---------------------------------------------------------------------------
// Kernel 2: attention = R7 structure + frag-linear LDS, scratch-free staging.
// grid = 256 (bh = bid&7 per XCD; 32 q-tiles of 128), block = 1024 = 16 waves:
// KV-split 4 (group g = wave>>2, chunks ≡ g mod 4) x 4 q-waves, Q=32/wave.
// LDS 130KB: [parity][K/V][grp][8 frags x FRAG]; frag-linear reads
// (base + lane*16 + f*1040B, conflict-free, offsets fold to immediates).
// Staging uses NAMED SCALARS only (kA..vB, offA/offB): R8-R10's macro
// arrays (kst[2]/off[2]) went to scratch (rule #20) -> 140MB/dispatch
// of HBM scratch traffic, which was the whole regression.
// ---------------------------------------------------------------------------
__global__ __launch_bounds__(1024) void attn(
    const unsigned short* __restrict__ Qh,
    const unsigned short* __restrict__ Kh,
    const unsigned short* __restrict__ Vt,
    float* __restrict__ out)
{
  __shared__ unsigned short KV[2][2][4][8 * FRAG];  // [parity][K/V][grp][slots]

  const int tid = threadIdx.x;
  const int ln  = tid & 63;
  const int wv  = tid >> 6;       // 0..15
  const int g   = wv >> 2;        // KV group 0..3
  const int wq  = wv & 3;         // q sub-tile
  const int r32 = ln & 31;
  const int h   = ln >> 5;

  const int bid = blockIdx.x;
  const int bh  = bid & 7;                 // XCD-local bh
  const int q0  = (bid >> 3) * 128;

  const unsigned short* Qb = Qh + (size_t)bh * S_LEN * DH;
  const unsigned short* Kb = Kh + (size_t)bh * S_LEN * DH;
  const unsigned short* Vb = Vt + (size_t)bh * DH * S_LEN;

  // Q as B-operand of swapped QK: lane holds Q[q=r32][d = s*16 + h*8 + j]
  const int q = q0 + wq * 32 + r32;
  bf16x8 qf[4];
#pragma unroll
  for (int s = 0; s < 4; ++s)
    qf[s] = *(const bf16x8*)(Qb + (size_t)q * DH + s * 16 + h * 8);

  f32x16 o0 = {}, o1 = {};     // o^T: col=q, rows=d (two 32-d tiles)
  float l_run = 0.f;

  // ---- staging (named scalars only; no arrays -> no scratch) ----
  const int u  = tid & 255;
  const int gs = tid >> 8;         // staging group == own wave's g
  const int sr = u >> 2;           // row 0..63 (t for K, d for V^T)
  const int sc = (u & 3) * 16;     // ushort col
  // frag-scatter offsets (verified bijection, R8-R10 absmax-passed):
  //   piece A (d0=sc):   f0 = (sc>>4)*2 + (sr>>5), lane (sr&31)
  //   piece B (d0=sc+8): same f0, lane (sr&31)+32
  const int f0   = (sc >> 4) * 2 + (sr >> 5);
  const int offA = f0 * FRAG + (sr & 31) * 8;
  const int offB = offA + 256;

  uint4 kA, kB, vA, vB;
#define LOAD_CHUNK(c)                                                          \
  { const unsigned short* kp = Kb + ((size_t)(c) * 64 + sr) * DH + sc;         \
    kA = *(const uint4*)kp;  kB = *(const uint4*)(kp + 8);                     \
    const unsigned short* vp = Vb + (size_t)sr * S_LEN + (c) * 64 + sc;        \
    vA = *(const uint4*)vp;  vB = *(const uint4*)(vp + 8); }
#define STAGE(par)                                                             \
  { unsigned short* kd = &KV[par][0][gs][0];                                   \
    *(uint4*)(kd + offA) = kA;  *(uint4*)(kd + offB) = kB;                     \
    unsigned short* vd = &KV[par][1][gs][0];                                   \
    *(uint4*)(vd + offA) = vA;  *(uint4*)(vd + offB) = vB; }

  LOAD_CHUNK(gs);
  STAGE(0);
  LOAD_CHUNK(4 + gs);

  for (int it = 0; it < 16; ++it) {
    __syncthreads();   // parity-(it&1) writes visible; prior same-parity reads done
    if (it < 15) {     // stage chunk for it+1 into the other parity buffer
      STAGE((it + 1) & 1);
      int c = 4 * (it + 2) + gs;  if (c > 63) c = 63;   // prefetch for it+2
      LOAD_CHUNK(c);
    }
    const unsigned short* Kc = &KV[it & 1][0][g][0];
    const unsigned short* Vc = &KV[it & 1][1][g][0];
    const int lb = ln * 8;

    // ---- QK^T (swapped, 32x32x16): S^T[t][q], t-halves 0/1 ----
    f32x16 s0 = {}, s1 = {};
    __builtin_amdgcn_s_setprio(1);
#pragma unroll
    for (int s = 0; s < 4; ++s) {
      bf16x8 a0 = *(const bf16x8*)(Kc + lb + (2 * s + 0) * FRAG);
      bf16x8 a1 = *(const bf16x8*)(Kc + lb + (2 * s + 1) * FRAG);
      s0 = MFMA32(a0, qf[s], s0);
      s1 = MFMA32(a1, qf[s], s1);
    }
    __builtin_amdgcn_s_setprio(0);

    // ---- P = exp2(S^T) (no max-subtraction: logits provably bounded) ----
    float ps = 0.f;
#pragma unroll
    for (int i = 0; i < 16; ++i) {
      s0[i] = __builtin_amdgcn_exp2f(s0[i]);  ps += s0[i];
      s1[i] = __builtin_amdgcn_exp2f(s1[i]);  ps += s1[i];
    }
    l_run += ps;

    // ---- P(f32 C-layout) -> bf16 B-operand frags ----
    bf16x8 pb[4];
    pack_pb(s0, s1, pb);

    // ---- PV (swapped): o^T[d][q] += V^T[d][t] * P^T[t][q] ----
    __builtin_amdgcn_s_setprio(1);
#pragma unroll
    for (int s = 0; s < 4; ++s) {
      bf16x8 b0 = *(const bf16x8*)(Vc + lb + (2 * s + 0) * FRAG);
      bf16x8 b1 = *(const bf16x8*)(Vc + lb + (2 * s + 1) * FRAG);
      o0 = MFMA32(b0, pb[s], o0);
      o1 = MFMA32(b1, pb[s], o1);
    }
    __builtin_amdgcn_s_setprio(0);
  }

  // ---- KV-split combine: 4 -> 2 -> 1 (exact: partials additive) ----
  __syncthreads();                            // last computes done
  float* cb = (float*)&KV[0][0][0][0];        // scratch; rounds use <70KB
  const int cbase = wq * 64 + ln;             // 0..255

  // round 1: groups 2,3 publish; groups 0,1 absorb
  if (g >= 2) {
    const int base = ((g - 2) * 256 + cbase) * 33;
#pragma unroll
    for (int i = 0; i < 16; ++i) { cb[base + i] = o0[i]; cb[base + 16 + i] = o1[i]; }
    cb[base + 32] = l_run;
  }
  __syncthreads();
  if (g < 2) {
    const int base = (g * 256 + cbase) * 33;
#pragma unroll
    for (int i = 0; i < 16; ++i) { o0[i] += cb[base + i]; o1[i] += cb[base + 16 + i]; }
    l_run += cb[base + 32];
  }
  __syncthreads();
  // round 2: group 1 publishes; group 0 absorbs
  if (g == 1) {
    const int base = cbase * 33;
#pragma unroll
    for (int i = 0; i < 16; ++i) { cb[base + i] = o0[i]; cb[base + 16 + i] = o1[i]; }
    cb[base + 32] = l_run;
  }
  __syncthreads();
  if (g == 0) {
    const int base = cbase * 33;
#pragma unroll
    for (int i = 0; i < 16; ++i) { o0[i] += cb[base + i]; o1[i] += cb[base + 16 + i]; }
    l_run += cb[base + 32];

    // ---- epilogue: l across h-halves, normalize, store ----
    const float lt  = l_run + __shfl_xor(l_run, 32);
    const float inv = 1.f / lt;
    const int bb = bh >> 2, hd = bh & 3;
    float* op = out + ((size_t)(bb * S_LEN + q)) * D_MODEL + hd * DH;
#pragma unroll
    for (int gg = 0; gg < 4; ++gg) {
      float4 v0, v1;
      v0.x = o0[4 * gg + 0] * inv;  v0.y = o0[4 * gg + 1] * inv;
      v0.z = o0[4 * gg + 2] * inv;  v0.w = o0[4 * gg + 3] * inv;
      *(float4*)(op + 8 * gg + 4 * h) = v0;
      v1.x = o1[4 * gg + 0] * inv;  v1.y = o1[4 * gg + 1] * inv;
      v1.z = o1[4 * gg + 2] * inv;  v1.w = o1[4 * gg + 3] * inv;
      *(float4*)(op + 32 + 8 * gg + 4 * h) = v1;
    }
  }
}

// ---------------------------------------------------------------------------
extern "C" void kernel_launch(void* const* d_in, const int* in_sizes, int n_in,
                              void* d_out, int out_size, void* d_ws, size_t ws_size,
                              hipStream_t stream) {
  const float* x  = (const float*)d_in[0];
  const float* Wq = (const float*)d_in[1];
  const float* bq = (const float*)d_in[2];
  const float* Wk = (const float*)d_in[3];
  const float* bk = (const float*)d_in[4];
  const float* Wv = (const float*)d_in[5];
  const float* bv = (const float*)d_in[6];
  float* out = (float*)d_out;

  const size_t per = (size_t)2 * NH * S_LEN * DH;       // 2M bf16 elems each
  if (ws_size < 3 * per * sizeof(unsigned short)) return;
  unsigned short* Qh = (unsigned short*)d_ws;
  unsigned short* Kh = Qh + per;
  unsigned short* Vt = Kh + per;
  unsigned short* Wb = (unsigned short*)d_out;   // scratch; attn overwrites out

  prep<<<96, 256, 0, stream>>>(Wq, Wk, Wv, Wb);
  qkv_proj<<<512, 256, 0, stream>>>(x, Wb, bq, bk, bv, Qh, Kh, Vt);
  attn<<<256, 1024, 0, stream>>>(Qh, Kh, Vt, out);
}

// Round 14
// 62.177 us; speedup vs baseline: 1.8007x; 1.0732x over previous
//
#include <hip/hip_runtime.h>

#define S_LEN 4096
#define D_MODEL 256
#define NH 4
#define DH 64
#define CSC 0.18033688011112042f   // log2(e) / sqrt(64)
#define FRAG 520                   // ushorts per fragment slot (512 + 8 pad)

typedef __attribute__((ext_vector_type(8))) short bf16x8;
typedef __attribute__((ext_vector_type(8))) unsigned short u16x8;
typedef __attribute__((ext_vector_type(4))) float f32x4;
typedef __attribute__((ext_vector_type(16))) float f32x16;
typedef __attribute__((ext_vector_type(2))) unsigned int u32x2;
typedef __attribute__((ext_vector_type(4))) unsigned int u32x4;

#define MFMA16(a, b, c) __builtin_amdgcn_mfma_f32_16x16x32_bf16((a), (b), (c), 0, 0, 0)
#define MFMA32(a, b, c) __builtin_amdgcn_mfma_f32_32x32x16_bf16((a), (b), (c), 0, 0, 0)

static __device__ __forceinline__ unsigned short f2bf(float f) {
  unsigned int u = __float_as_uint(f);
  u += 0x7fffu + ((u >> 16) & 1u);   // RTNE
  return (unsigned short)(u >> 16);
}

static __device__ __forceinline__ unsigned int cvtpk(float lo, float hi) {
  unsigned int r;
  asm("v_cvt_pk_bf16_f32 %0, %1, %2" : "=v"(r) : "v"(lo), "v"(hi));
  return r;   // lo -> [15:0], hi -> [31:16], RTNE
}

static __device__ __forceinline__ u16x8 cvt8(float4 a, float4 b) {
  u16x8 v;
  v[0] = f2bf(a.x); v[1] = f2bf(a.y); v[2] = f2bf(a.z); v[3] = f2bf(a.w);
  v[4] = f2bf(b.x); v[5] = f2bf(b.y); v[6] = f2bf(b.z); v[7] = f2bf(b.w);
  return v;
}

// P(f32 C-layout, two 32-row t-tiles) -> 4 bf16 B-operand fragments
static __device__ __forceinline__ void pack_pb(const f32x16& s0, const f32x16& s1,
                                               bf16x8* pb) {
  unsigned int u0[8], u1[8];
#pragma unroll
  for (int gg = 0; gg < 4; ++gg) {
    u0[gg * 2 + 0] = cvtpk(s0[4 * gg + 0], s0[4 * gg + 1]);
    u0[gg * 2 + 1] = cvtpk(s0[4 * gg + 2], s0[4 * gg + 3]);
    u1[gg * 2 + 0] = cvtpk(s1[4 * gg + 0], s1[4 * gg + 1]);
    u1[gg * 2 + 1] = cvtpk(s1[4 * gg + 2], s1[4 * gg + 3]);
  }
#pragma unroll
  for (int S = 0; S < 2; ++S) {
    u32x2 w0 = __builtin_amdgcn_permlane32_swap(u0[4 * S + 0], u0[4 * S + 2], false, false);
    u32x2 w1 = __builtin_amdgcn_permlane32_swap(u0[4 * S + 1], u0[4 * S + 3], false, false);
    u32x4 t0; t0[0] = w0[0]; t0[1] = w1[0]; t0[2] = w0[1]; t0[3] = w1[1];
    pb[S] = __builtin_bit_cast(bf16x8, t0);
    u32x2 w2 = __builtin_amdgcn_permlane32_swap(u1[4 * S + 0], u1[4 * S + 2], false, false);
    u32x2 w3 = __builtin_amdgcn_permlane32_swap(u1[4 * S + 1], u1[4 * S + 3], false, false);
    u32x4 t1; t1[0] = w2[0]; t1[1] = w3[0]; t1[2] = w2[1]; t1[3] = w3[1];
    pb[2 + S] = __builtin_bit_cast(bf16x8, t1);
  }
}

// ---------------------------------------------------------------------------
// Kernel 0: convert W{q,k,v} to bf16 in MFMA-B-fragment order (16x16x32).
// ---------------------------------------------------------------------------
__global__ __launch_bounds__(256) void prep(
    const float* __restrict__ Wq, const float* __restrict__ Wk,
    const float* __restrict__ Wv, unsigned short* __restrict__ Wb)
{
  const int gid = blockIdx.x * 256 + threadIdx.x;
  const int l   = gid & 63;
  const int f   = gid >> 6;
  const int kk  = f & 7;
  const int ctn = f >> 3;
  const int ct  = ctn & 3, nt = ctn >> 2;
  const int pj  = nt >> 2, h = nt & 3;
  const float* Wsel = (pj == 0) ? Wq : (pj == 1) ? Wk : Wv;
  const float* src =
      Wsel + (size_t)(h * 64 + ct * 16 + (l & 15)) * D_MODEL + kk * 32 + (l >> 4) * 8;
  float4 a = *(const float4*)src;
  float4 b = *(const float4*)(src + 4);
  *(u16x8*)(Wb + (size_t)gid * 8) = cvt8(a, b);
}

// ---------------------------------------------------------------------------
// Kernel 1: QKV projection with block-transpose coalesced stores.
// Q pre-scaled by CSC; V written transposed Vt[bh][d][s].
// ---------------------------------------------------------------------------
__global__ __launch_bounds__(256) void qkv_proj(
    const float* __restrict__ x, const unsigned short* __restrict__ Wb,
    const float* __restrict__ bq, const float* __restrict__ bk,
    const float* __restrict__ bv,
    unsigned short* __restrict__ Qh, unsigned short* __restrict__ Kh,
    unsigned short* __restrict__ Vt)
{
  __shared__ unsigned short xs[32][264];
  __shared__ float tbuf[32][68];          // block transpose buffer

  const int tid  = threadIdx.x;
  const int lane = tid & 63;
  const int w    = tid >> 6;
  const int r16  = lane & 15;
  const int hi   = lane >> 4;
  const int m0   = (blockIdx.x >> 1) * 32;
  const int ntB  = (blockIdx.x & 1) * 6;

  {  // stage x tile: 32 rows x 256 f32 -> bf16
    const int r  = tid >> 3;
    const int c0 = (tid & 7) * 32;
    const float* xp = x + (size_t)(m0 + r) * D_MODEL + c0;
#pragma unroll
    for (int i = 0; i < 32; i += 8) {
      float4 a = *(const float4*)(xp + i);
      float4 b = *(const float4*)(xp + i + 4);
      *(u16x8*)&xs[r][c0 + i] = cvt8(a, b);
    }
  }
  __syncthreads();

  const int bb = m0 >> 12;
  const int s_base = m0 & 4095;

  for (int t = 0; t < 6; ++t) {
    const int nt = ntB + t, pj = nt >> 2, h = nt & 3;
    f32x4 acc[2] = {};
    const size_t fb = (size_t)(nt * 4 + w) * 8;
#pragma unroll
    for (int kk = 0; kk < 8; ++kk) {
      bf16x8 bw = *(const bf16x8*)(Wb + (fb + kk) * 512 + lane * 8);
#pragma unroll
      for (int rt = 0; rt < 2; ++rt) {
        bf16x8 af = *(const bf16x8*)&xs[rt * 16 + r16][kk * 32 + hi * 8];
        acc[rt] = MFMA16(af, bw, acc[rt]);
      }
    }
    const float* bsel = (pj == 0) ? bq : (pj == 1) ? bk : bv;
    const float bias = bsel[h * 64 + w * 16 + r16];
    const float scl  = (pj == 0) ? CSC : 1.0f;

    // scatter into f32 transpose buffer [s_local][e_local]
#pragma unroll
    for (int rt = 0; rt < 2; ++rt)
#pragma unroll
      for (int j = 0; j < 4; ++j)
        tbuf[rt * 16 + hi * 4 + j][w * 16 + r16] = (acc[rt][j] + bias) * scl;
    __syncthreads();

    if (pj < 2) {   // coalesced 128B-row stores: thread -> (s_l, 8 cols)
      const int s_l = tid >> 3, c0 = (tid & 7) * 8;
      float4 a = *(const float4*)&tbuf[s_l][c0];
      float4 b = *(const float4*)&tbuf[s_l][c0 + 4];
      unsigned short* dst = ((pj == 0) ? Qh : Kh) +
          ((size_t)(bb * NH + h) * S_LEN + s_base + s_l) * DH + c0;
      *(u16x8*)dst = cvt8(a, b);
    } else {        // V transposed: thread -> (d_l, 8 s)
      const int d_l = tid & 63, sblk = (tid >> 6) * 8;
      u16x8 vv;
#pragma unroll
      for (int e = 0; e < 8; ++e) vv[e] = f2bf(tbuf[sblk + e][d_l]);
      unsigned short* dst = Vt +
          ((size_t)(bb * NH + h) * DH + d_l) * S_LEN + s_base + sblk;
      *(u16x8*)dst = vv;
    }
    __syncthreads();
  }
}

// ---------------------------------------------------------------------------
// Kernel 2: attention. R11 structure with DS-queue-aware ordering:
// per iteration, K ds_reads (QK) issue FIRST into an empty DS queue; the
// STAGE ds_writes are placed in the exp2 VALU phase (DS pipe idle there);
// V ds_reads (PV) follow pack. LDS arrays may-alias so the compiler honors
// this source order. Softmax sum uses 4 accumulators (8-deep chains, not 32).
// grid = 256 (bh = bid&7 per XCD; 32 q-tiles of 128), 1024 thr = 16 waves
// (4 KV-groups x 4 q-waves), frag-linear LDS (conflict-free, R11-verified),
// named-scalar staging (no scratch), no-max softmax, combine 4->2->1.
// ---------------------------------------------------------------------------
__global__ __launch_bounds__(1024) void attn(
    const unsigned short* __restrict__ Qh,
    const unsigned short* __restrict__ Kh,
    const unsigned short* __restrict__ Vt,
    float* __restrict__ out)
{
  __shared__ unsigned short KV[2][2][4][8 * FRAG];  // [parity][K/V][grp][slots]

  const int tid = threadIdx.x;
  const int ln  = tid & 63;
  const int wv  = tid >> 6;       // 0..15
  const int g   = wv >> 2;        // KV group 0..3
  const int wq  = wv & 3;         // q sub-tile
  const int r32 = ln & 31;
  const int h   = ln >> 5;

  const int bid = blockIdx.x;
  const int bh  = bid & 7;                 // XCD-local bh
  const int q0  = (bid >> 3) * 128;

  const unsigned short* Qb = Qh + (size_t)bh * S_LEN * DH;
  const unsigned short* Kb = Kh + (size_t)bh * S_LEN * DH;
  const unsigned short* Vb = Vt + (size_t)bh * DH * S_LEN;

  // Q as B-operand of swapped QK: lane holds Q[q=r32][d = s*16 + h*8 + j]
  const int q = q0 + wq * 32 + r32;
  bf16x8 qf[4];
#pragma unroll
  for (int s = 0; s < 4; ++s)
    qf[s] = *(const bf16x8*)(Qb + (size_t)q * DH + s * 16 + h * 8);

  f32x16 o0 = {}, o1 = {};     // o^T: col=q, rows=d (two 32-d tiles)
  float l_run = 0.f;

  // ---- staging (named scalars only; no arrays -> no scratch) ----
  const int u  = tid & 255;
  const int gs = tid >> 8;         // staging group == own wave's g
  const int sr = u >> 2;           // row 0..63 (t for K, d for V^T)
  const int sc = (u & 3) * 16;     // ushort col
  // frag-scatter offsets (verified bijection, R8-R11 absmax-passed)
  const int f0   = (sc >> 4) * 2 + (sr >> 5);
  const int offA = f0 * FRAG + (sr & 31) * 8;
  const int offB = offA + 256;

  uint4 kA, kB, vA, vB;
#define LOAD_CHUNK(c)                                                          \
  { const unsigned short* kp = Kb + ((size_t)(c) * 64 + sr) * DH + sc;         \
    kA = *(const uint4*)kp;  kB = *(const uint4*)(kp + 8);                     \
    const unsigned short* vp = Vb + (size_t)sr * S_LEN + (c) * 64 + sc;        \
    vA = *(const uint4*)vp;  vB = *(const uint4*)(vp + 8); }
#define STAGE(par)                                                             \
  { unsigned short* kd = &KV[par][0][gs][0];                                   \
    *(uint4*)(kd + offA) = kA;  *(uint4*)(kd + offB) = kB;                     \
    unsigned short* vd = &KV[par][1][gs][0];                                   \
    *(uint4*)(vd + offA) = vA;  *(uint4*)(vd + offB) = vB; }

  LOAD_CHUNK(gs);
  STAGE(0);
  LOAD_CHUNK(4 + gs);

  for (int it = 0; it < 16; ++it) {
    __syncthreads();   // parity-(it&1) writes visible; prior same-parity reads done
    const unsigned short* Kc = &KV[it & 1][0][g][0];
    const unsigned short* Vc = &KV[it & 1][1][g][0];
    const int lb = ln * 8;

    // ---- QK^T first: K ds_reads hit an empty DS queue ----
    f32x16 s0 = {}, s1 = {};
    __builtin_amdgcn_s_setprio(1);
#pragma unroll
    for (int s = 0; s < 4; ++s) {
      bf16x8 a0 = *(const bf16x8*)(Kc + lb + (2 * s + 0) * FRAG);
      bf16x8 a1 = *(const bf16x8*)(Kc + lb + (2 * s + 1) * FRAG);
      s0 = MFMA32(a0, qf[s], s0);
      s1 = MFMA32(a1, qf[s], s1);
    }
    __builtin_amdgcn_s_setprio(0);

    // ---- P = exp2(S^T), 4-way tree sum (8-deep chains) ----
    float pa = 0.f, pbs = 0.f, pc = 0.f, pd = 0.f;
#pragma unroll
    for (int i = 0; i < 16; i += 2) {
      s0[i]     = __builtin_amdgcn_exp2f(s0[i]);      pa  += s0[i];
      s0[i + 1] = __builtin_amdgcn_exp2f(s0[i + 1]);  pbs += s0[i + 1];
      s1[i]     = __builtin_amdgcn_exp2f(s1[i]);      pc  += s1[i];
      s1[i + 1] = __builtin_amdgcn_exp2f(s1[i + 1]);  pd  += s1[i + 1];
    }
    l_run += (pa + pbs) + (pc + pd);

    // ---- STAGE ds_writes land during the VALU phase (DS pipe idle) ----
    if (it < 15) {
      STAGE((it + 1) & 1);
      int c = 4 * (it + 2) + gs;  if (c > 63) c = 63;   // prefetch for it+2
      LOAD_CHUNK(c);
    }

    // ---- P(f32 C-layout) -> bf16 B-operand frags ----
    bf16x8 pb[4];
    pack_pb(s0, s1, pb);

    // ---- PV (swapped): o^T[d][q] += V^T[d][t] * P^T[t][q] ----
    __builtin_amdgcn_s_setprio(1);
#pragma unroll
    for (int s = 0; s < 4; ++s) {
      bf16x8 b0 = *(const bf16x8*)(Vc + lb + (2 * s + 0) * FRAG);
      bf16x8 b1 = *(const bf16x8*)(Vc + lb + (2 * s + 1) * FRAG);
      o0 = MFMA32(b0, pb[s], o0);
      o1 = MFMA32(b1, pb[s], o1);
    }
    __builtin_amdgcn_s_setprio(0);
  }

  // ---- KV-split combine: 4 -> 2 -> 1 (exact: partials additive) ----
  __syncthreads();                            // last computes done
  float* cb = (float*)&KV[0][0][0][0];        // scratch; rounds use <70KB
  const int cbase = wq * 64 + ln;             // 0..255

  // round 1: groups 2,3 publish; groups 0,1 absorb
  if (g >= 2) {
    const int base = ((g - 2) * 256 + cbase) * 33;
#pragma unroll
    for (int i = 0; i < 16; ++i) { cb[base + i] = o0[i]; cb[base + 16 + i] = o1[i]; }
    cb[base + 32] = l_run;
  }
  __syncthreads();
  if (g < 2) {
    const int base = (g * 256 + cbase) * 33;
#pragma unroll
    for (int i = 0; i < 16; ++i) { o0[i] += cb[base + i]; o1[i] += cb[base + 16 + i]; }
    l_run += cb[base + 32];
  }
  __syncthreads();
  // round 2: group 1 publishes; group 0 absorbs
  if (g == 1) {
    const int base = cbase * 33;
#pragma unroll
    for (int i = 0; i < 16; ++i) { cb[base + i] = o0[i]; cb[base + 16 + i] = o1[i]; }
    cb[base + 32] = l_run;
  }
  __syncthreads();
  if (g == 0) {
    const int base = cbase * 33;
#pragma unroll
    for (int i = 0; i < 16; ++i) { o0[i] += cb[base + i]; o1[i] += cb[base + 16 + i]; }
    l_run += cb[base + 32];

    // ---- epilogue: l across h-halves, normalize, store ----
    const float lt  = l_run + __shfl_xor(l_run, 32);
    const float inv = 1.f / lt;
    const int bb = bh >> 2, hd = bh & 3;
    float* op = out + ((size_t)(bb * S_LEN + q)) * D_MODEL + hd * DH;
#pragma unroll
    for (int gg = 0; gg < 4; ++gg) {
      float4 v0, v1;
      v0.x = o0[4 * gg + 0] * inv;  v0.y = o0[4 * gg + 1] * inv;
      v0.z = o0[4 * gg + 2] * inv;  v0.w = o0[4 * gg + 3] * inv;
      *(float4*)(op + 8 * gg + 4 * h) = v0;
      v1.x = o1[4 * gg + 0] * inv;  v1.y = o1[4 * gg + 1] * inv;
      v1.z = o1[4 * gg + 2] * inv;  v1.w = o1[4 * gg + 3] * inv;
      *(float4*)(op + 32 + 8 * gg + 4 * h) = v1;
    }
  }
}

// ---------------------------------------------------------------------------
extern "C" void kernel_launch(void* const* d_in, const int* in_sizes, int n_in,
                              void* d_out, int out_size, void* d_ws, size_t ws_size,
                              hipStream_t stream) {
  const float* x  = (const float*)d_in[0];
  const float* Wq = (const float*)d_in[1];
  const float* bq = (const float*)d_in[2];
  const float* Wk = (const float*)d_in[3];
  const float* bk = (const float*)d_in[4];
  const float* Wv = (const float*)d_in[5];
  const float* bv = (const float*)d_in[6];
  float* out = (float*)d_out;

  const size_t per = (size_t)2 * NH * S_LEN * DH;       // 2M bf16 elems each
  if (ws_size < 3 * per * sizeof(unsigned short)) return;
  unsigned short* Qh = (unsigned short*)d_ws;
  unsigned short* Kh = Qh + per;
  unsigned short* Vt = Kh + per;
  unsigned short* Wb = (unsigned short*)d_out;   // scratch; attn overwrites out

  prep<<<96, 256, 0, stream>>>(Wq, Wk, Wv, Wb);
  qkv_proj<<<512, 256, 0, stream>>>(x, Wb, bq, bk, bv, Qh, Kh, Vt);
  attn<<<256, 1024, 0, stream>>>(Qh, Kh, Vt, out);
}

// Round 18
// 62.016 us; speedup vs baseline: 1.8054x; 1.0026x over previous
//
#include <hip/hip_runtime.h>

#define S_LEN 4096
#define D_MODEL 256
#define NH 4
#define DH 64
#define CSC 0.18033688011112042f   // log2(e) / sqrt(64)
#define FRAG 520                   // ushorts per fragment slot (512 + 8 pad)

typedef __attribute__((ext_vector_type(8))) short bf16x8;
typedef __attribute__((ext_vector_type(8))) unsigned short u16x8;
typedef __attribute__((ext_vector_type(4))) float f32x4;
typedef __attribute__((ext_vector_type(16))) float f32x16;
typedef __attribute__((ext_vector_type(2))) unsigned int u32x2;
typedef __attribute__((ext_vector_type(4))) unsigned int u32x4;

#define MFMA16(a, b, c) __builtin_amdgcn_mfma_f32_16x16x32_bf16((a), (b), (c), 0, 0, 0)
#define MFMA32(a, b, c) __builtin_amdgcn_mfma_f32_32x32x16_bf16((a), (b), (c), 0, 0, 0)

static __device__ __forceinline__ unsigned short f2bf(float f) {
  unsigned int u = __float_as_uint(f);
  u += 0x7fffu + ((u >> 16) & 1u);   // RTNE
  return (unsigned short)(u >> 16);
}

static __device__ __forceinline__ unsigned int cvtpk(float lo, float hi) {
  unsigned int r;
  asm("v_cvt_pk_bf16_f32 %0, %1, %2" : "=v"(r) : "v"(lo), "v"(hi));
  return r;   // lo -> [15:0], hi -> [31:16], RTNE
}

static __device__ __forceinline__ u16x8 cvt8(float4 a, float4 b) {
  u16x8 v;
  v[0] = f2bf(a.x); v[1] = f2bf(a.y); v[2] = f2bf(a.z); v[3] = f2bf(a.w);
  v[4] = f2bf(b.x); v[5] = f2bf(b.y); v[6] = f2bf(b.z); v[7] = f2bf(b.w);
  return v;
}

// P(f32 C-layout, two 32-row t-tiles) -> 4 bf16 B-operand fragments
static __device__ __forceinline__ void pack_pb(const f32x16& s0, const f32x16& s1,
                                               bf16x8* pb) {
  unsigned int u0[8], u1[8];
#pragma unroll
  for (int gg = 0; gg < 4; ++gg) {
    u0[gg * 2 + 0] = cvtpk(s0[4 * gg + 0], s0[4 * gg + 1]);
    u0[gg * 2 + 1] = cvtpk(s0[4 * gg + 2], s0[4 * gg + 3]);
    u1[gg * 2 + 0] = cvtpk(s1[4 * gg + 0], s1[4 * gg + 1]);
    u1[gg * 2 + 1] = cvtpk(s1[4 * gg + 2], s1[4 * gg + 3]);
  }
#pragma unroll
  for (int S = 0; S < 2; ++S) {
    u32x2 w0 = __builtin_amdgcn_permlane32_swap(u0[4 * S + 0], u0[4 * S + 2], false, false);
    u32x2 w1 = __builtin_amdgcn_permlane32_swap(u0[4 * S + 1], u0[4 * S + 3], false, false);
    u32x4 t0; t0[0] = w0[0]; t0[1] = w1[0]; t0[2] = w0[1]; t0[3] = w1[1];
    pb[S] = __builtin_bit_cast(bf16x8, t0);
    u32x2 w2 = __builtin_amdgcn_permlane32_swap(u1[4 * S + 0], u1[4 * S + 2], false, false);
    u32x2 w3 = __builtin_amdgcn_permlane32_swap(u1[4 * S + 1], u1[4 * S + 3], false, false);
    u32x4 t1; t1[0] = w2[0]; t1[1] = w3[0]; t1[2] = w2[1]; t1[3] = w3[1];
    pb[2 + S] = __builtin_bit_cast(bf16x8, t1);
  }
}

// ---------------------------------------------------------------------------
// Kernel 0: convert W{q,k,v} to bf16 in MFMA-B-fragment order (16x16x32).
// ---------------------------------------------------------------------------
__global__ __launch_bounds__(256) void prep(
    const float* __restrict__ Wq, const float* __restrict__ Wk,
    const float* __restrict__ Wv, unsigned short* __restrict__ Wb)
{
  const int gid = blockIdx.x * 256 + threadIdx.x;
  const int l   = gid & 63;
  const int f   = gid >> 6;
  const int kk  = f & 7;
  const int ctn = f >> 3;
  const int ct  = ctn & 3, nt = ctn >> 2;
  const int pj  = nt >> 2, h = nt & 3;
  const float* Wsel = (pj == 0) ? Wq : (pj == 1) ? Wk : Wv;
  const float* src =
      Wsel + (size_t)(h * 64 + ct * 16 + (l & 15)) * D_MODEL + kk * 32 + (l >> 4) * 8;
  float4 a = *(const float4*)src;
  float4 b = *(const float4*)(src + 4);
  *(u16x8*)(Wb + (size_t)gid * 8) = cvt8(a, b);
}

// ---------------------------------------------------------------------------
// Kernel 1: QKV projection with block-transpose coalesced stores.
// Q pre-scaled by CSC; V written transposed Vt[bh][d][s].
// ---------------------------------------------------------------------------
__global__ __launch_bounds__(256) void qkv_proj(
    const float* __restrict__ x, const unsigned short* __restrict__ Wb,
    const float* __restrict__ bq, const float* __restrict__ bk,
    const float* __restrict__ bv,
    unsigned short* __restrict__ Qh, unsigned short* __restrict__ Kh,
    unsigned short* __restrict__ Vt)
{
  __shared__ unsigned short xs[32][264];
  __shared__ float tbuf[32][68];          // block transpose buffer

  const int tid  = threadIdx.x;
  const int lane = tid & 63;
  const int w    = tid >> 6;
  const int r16  = lane & 15;
  const int hi   = lane >> 4;
  const int m0   = (blockIdx.x >> 1) * 32;
  const int ntB  = (blockIdx.x & 1) * 6;

  {  // stage x tile: 32 rows x 256 f32 -> bf16
    const int r  = tid >> 3;
    const int c0 = (tid & 7) * 32;
    const float* xp = x + (size_t)(m0 + r) * D_MODEL + c0;
#pragma unroll
    for (int i = 0; i < 32; i += 8) {
      float4 a = *(const float4*)(xp + i);
      float4 b = *(const float4*)(xp + i + 4);
      *(u16x8*)&xs[r][c0 + i] = cvt8(a, b);
    }
  }
  __syncthreads();

  const int bb = m0 >> 12;
  const int s_base = m0 & 4095;

  for (int t = 0; t < 6; ++t) {
    const int nt = ntB + t, pj = nt >> 2, h = nt & 3;
    f32x4 acc[2] = {};
    const size_t fb = (size_t)(nt * 4 + w) * 8;
#pragma unroll
    for (int kk = 0; kk < 8; ++kk) {
      bf16x8 bw = *(const bf16x8*)(Wb + (fb + kk) * 512 + lane * 8);
#pragma unroll
      for (int rt = 0; rt < 2; ++rt) {
        bf16x8 af = *(const bf16x8*)&xs[rt * 16 + r16][kk * 32 + hi * 8];
        acc[rt] = MFMA16(af, bw, acc[rt]);
      }
    }
    const float* bsel = (pj == 0) ? bq : (pj == 1) ? bk : bv;
    const float bias = bsel[h * 64 + w * 16 + r16];
    const float scl  = (pj == 0) ? CSC : 1.0f;

    // scatter into f32 transpose buffer [s_local][e_local]
#pragma unroll
    for (int rt = 0; rt < 2; ++rt)
#pragma unroll
      for (int j = 0; j < 4; ++j)
        tbuf[rt * 16 + hi * 4 + j][w * 16 + r16] = (acc[rt][j] + bias) * scl;
    __syncthreads();

    if (pj < 2) {   // coalesced 128B-row stores: thread -> (s_l, 8 cols)
      const int s_l = tid >> 3, c0 = (tid & 7) * 8;
      float4 a = *(const float4*)&tbuf[s_l][c0];
      float4 b = *(const float4*)&tbuf[s_l][c0 + 4];
      unsigned short* dst = ((pj == 0) ? Qh : Kh) +
          ((size_t)(bb * NH + h) * S_LEN + s_base + s_l) * DH + c0;
      *(u16x8*)dst = cvt8(a, b);
    } else {        // V transposed: thread -> (d_l, 8 s)
      const int d_l = tid & 63, sblk = (tid >> 6) * 8;
      u16x8 vv;
#pragma unroll
      for (int e = 0; e < 8; ++e) vv[e] = f2bf(tbuf[sblk + e][d_l]);
      unsigned short* dst = Vt +
          ((size_t)(bb * NH + h) * DH + d_l) * S_LEN + s_base + sblk;
      *(u16x8*)dst = vv;
    }
    __syncthreads();
  }
}

// ---------------------------------------------------------------------------
// Kernel 2: attention. R14 baseline (last measured-passing: 41.8us attn).
// DS-queue-aware ordering: K ds_reads (QK) issue FIRST after the barrier;
// STAGE ds_writes land during the exp2 VALU phase; V ds_reads follow pack.
// Softmax sum uses 4 accumulators. grid = 256 (bh = bid&7 per XCD; 32
// q-tiles of 128), 1024 thr = 16 waves (4 KV-groups x 4 q-waves),
// frag-linear LDS (conflict-free), named-scalar staging (no scratch),
// no-max softmax, combine 4->2->1.
// NOTE: R17's V-frag register prefetch (vr[8] before STAGE) FAILED absmax
// (7.9e-2) on this structure — reverted pending race isolation.
// ---------------------------------------------------------------------------
__global__ __launch_bounds__(1024) void attn(
    const unsigned short* __restrict__ Qh,
    const unsigned short* __restrict__ Kh,
    const unsigned short* __restrict__ Vt,
    float* __restrict__ out)
{
  __shared__ unsigned short KV[2][2][4][8 * FRAG];  // [parity][K/V][grp][slots]

  const int tid = threadIdx.x;
  const int ln  = tid & 63;
  const int wv  = tid >> 6;       // 0..15
  const int g   = wv >> 2;        // KV group 0..3
  const int wq  = wv & 3;         // q sub-tile
  const int r32 = ln & 31;
  const int h   = ln >> 5;

  const int bid = blockIdx.x;
  const int bh  = bid & 7;                 // XCD-local bh
  const int q0  = (bid >> 3) * 128;

  const unsigned short* Qb = Qh + (size_t)bh * S_LEN * DH;
  const unsigned short* Kb = Kh + (size_t)bh * S_LEN * DH;
  const unsigned short* Vb = Vt + (size_t)bh * DH * S_LEN;

  // Q as B-operand of swapped QK: lane holds Q[q=r32][d = s*16 + h*8 + j]
  const int q = q0 + wq * 32 + r32;
  bf16x8 qf[4];
#pragma unroll
  for (int s = 0; s < 4; ++s)
    qf[s] = *(const bf16x8*)(Qb + (size_t)q * DH + s * 16 + h * 8);

  f32x16 o0 = {}, o1 = {};     // o^T: col=q, rows=d (two 32-d tiles)
  float l_run = 0.f;

  // ---- staging (named scalars only; no arrays -> no scratch) ----
  const int u  = tid & 255;
  const int gs = tid >> 8;         // staging group == own wave's g
  const int sr = u >> 2;           // row 0..63 (t for K, d for V^T)
  const int sc = (u & 3) * 16;     // ushort col
  // frag-scatter offsets (verified bijection, R8-R14 absmax-passed)
  const int f0   = (sc >> 4) * 2 + (sr >> 5);
  const int offA = f0 * FRAG + (sr & 31) * 8;
  const int offB = offA + 256;

  uint4 kA, kB, vA, vB;
#define LOAD_CHUNK(c)                                                          \
  { const unsigned short* kp = Kb + ((size_t)(c) * 64 + sr) * DH + sc;         \
    kA = *(const uint4*)kp;  kB = *(const uint4*)(kp + 8);                     \
    const unsigned short* vp = Vb + (size_t)sr * S_LEN + (c) * 64 + sc;        \
    vA = *(const uint4*)vp;  vB = *(const uint4*)(vp + 8); }
#define STAGE(par)                                                             \
  { unsigned short* kd = &KV[par][0][gs][0];                                   \
    *(uint4*)(kd + offA) = kA;  *(uint4*)(kd + offB) = kB;                     \
    unsigned short* vd = &KV[par][1][gs][0];                                   \
    *(uint4*)(vd + offA) = vA;  *(uint4*)(vd + offB) = vB; }

  LOAD_CHUNK(gs);
  STAGE(0);
  LOAD_CHUNK(4 + gs);

  for (int it = 0; it < 16; ++it) {
    __syncthreads();   // parity-(it&1) writes visible; prior same-parity reads done
    const unsigned short* Kc = &KV[it & 1][0][g][0];
    const unsigned short* Vc = &KV[it & 1][1][g][0];
    const int lb = ln * 8;

    // ---- QK^T first: K ds_reads hit an empty DS queue ----
    f32x16 s0 = {}, s1 = {};
    __builtin_amdgcn_s_setprio(1);
#pragma unroll
    for (int s = 0; s < 4; ++s) {
      bf16x8 a0 = *(const bf16x8*)(Kc + lb + (2 * s + 0) * FRAG);
      bf16x8 a1 = *(const bf16x8*)(Kc + lb + (2 * s + 1) * FRAG);
      s0 = MFMA32(a0, qf[s], s0);
      s1 = MFMA32(a1, qf[s], s1);
    }
    __builtin_amdgcn_s_setprio(0);

    // ---- P = exp2(S^T), 4-way tree sum (8-deep chains) ----
    float pa = 0.f, pbs = 0.f, pc = 0.f, pd = 0.f;
#pragma unroll
    for (int i = 0; i < 16; i += 2) {
      s0[i]     = __builtin_amdgcn_exp2f(s0[i]);      pa  += s0[i];
      s0[i + 1] = __builtin_amdgcn_exp2f(s0[i + 1]);  pbs += s0[i + 1];
      s1[i]     = __builtin_amdgcn_exp2f(s1[i]);      pc  += s1[i];
      s1[i + 1] = __builtin_amdgcn_exp2f(s1[i + 1]);  pd  += s1[i + 1];
    }
    l_run += (pa + pbs) + (pc + pd);

    // ---- STAGE ds_writes land during the VALU phase (DS pipe idle) ----
    if (it < 15) {
      STAGE((it + 1) & 1);
      int c = 4 * (it + 2) + gs;  if (c > 63) c = 63;   // prefetch for it+2
      LOAD_CHUNK(c);
    }

    // ---- P(f32 C-layout) -> bf16 B-operand frags ----
    bf16x8 pb[4];
    pack_pb(s0, s1, pb);

    // ---- PV (swapped): o^T[d][q] += V^T[d][t] * P^T[t][q] ----
    __builtin_amdgcn_s_setprio(1);
#pragma unroll
    for (int s = 0; s < 4; ++s) {
      bf16x8 b0 = *(const bf16x8*)(Vc + lb + (2 * s + 0) * FRAG);
      bf16x8 b1 = *(const bf16x8*)(Vc + lb + (2 * s + 1) * FRAG);
      o0 = MFMA32(b0, pb[s], o0);
      o1 = MFMA32(b1, pb[s], o1);
    }
    __builtin_amdgcn_s_setprio(0);
  }

  // ---- KV-split combine: 4 -> 2 -> 1 (exact: partials additive) ----
  __syncthreads();                            // last computes done
  float* cb = (float*)&KV[0][0][0][0];        // scratch; rounds use <70KB
  const int cbase = wq * 64 + ln;             // 0..255

  // round 1: groups 2,3 publish; groups 0,1 absorb
  if (g >= 2) {
    const int base = ((g - 2) * 256 + cbase) * 33;
#pragma unroll
    for (int i = 0; i < 16; ++i) { cb[base + i] = o0[i]; cb[base + 16 + i] = o1[i]; }
    cb[base + 32] = l_run;
  }
  __syncthreads();
  if (g < 2) {
    const int base = (g * 256 + cbase) * 33;
#pragma unroll
    for (int i = 0; i < 16; ++i) { o0[i] += cb[base + i]; o1[i] += cb[base + 16 + i]; }
    l_run += cb[base + 32];
  }
  __syncthreads();
  // round 2: group 1 publishes; group 0 absorbs
  if (g == 1) {
    const int base = cbase * 33;
#pragma unroll
    for (int i = 0; i < 16; ++i) { cb[base + i] = o0[i]; cb[base + 16 + i] = o1[i]; }
    cb[base + 32] = l_run;
  }
  __syncthreads();
  if (g == 0) {
    const int base = cbase * 33;
#pragma unroll
    for (int i = 0; i < 16; ++i) { o0[i] += cb[base + i]; o1[i] += cb[base + 16 + i]; }
    l_run += cb[base + 32];

    // ---- epilogue: l across h-halves, normalize, store ----
    const float lt  = l_run + __shfl_xor(l_run, 32);
    const float inv = 1.f / lt;
    const int bb = bh >> 2, hd = bh & 3;
    float* op = out + ((size_t)(bb * S_LEN + q)) * D_MODEL + hd * DH;
#pragma unroll
    for (int gg = 0; gg < 4; ++gg) {
      float4 v0, v1;
      v0.x = o0[4 * gg + 0] * inv;  v0.y = o0[4 * gg + 1] * inv;
      v0.z = o0[4 * gg + 2] * inv;  v0.w = o0[4 * gg + 3] * inv;
      *(float4*)(op + 8 * gg + 4 * h) = v0;
      v1.x = o1[4 * gg + 0] * inv;  v1.y = o1[4 * gg + 1] * inv;
      v1.z = o1[4 * gg + 2] * inv;  v1.w = o1[4 * gg + 3] * inv;
      *(float4*)(op + 32 + 8 * gg + 4 * h) = v1;
    }
  }
}

// ---------------------------------------------------------------------------
extern "C" void kernel_launch(void* const* d_in, const int* in_sizes, int n_in,
                              void* d_out, int out_size, void* d_ws, size_t ws_size,
                              hipStream_t stream) {
  const float* x  = (const float*)d_in[0];
  const float* Wq = (const float*)d_in[1];
  const float* bq = (const float*)d_in[2];
  const float* Wk = (const float*)d_in[3];
  const float* bk = (const float*)d_in[4];
  const float* Wv = (const float*)d_in[5];
  const float* bv = (const float*)d_in[6];
  float* out = (float*)d_out;

  const size_t per = (size_t)2 * NH * S_LEN * DH;       // 2M bf16 elems each
  if (ws_size < 3 * per * sizeof(unsigned short)) return;
  unsigned short* Qh = (unsigned short*)d_ws;
  unsigned short* Kh = Qh + per;
  unsigned short* Vt = Kh + per;
  unsigned short* Wb = (unsigned short*)d_out;   // scratch; attn overwrites out

  prep<<<96, 256, 0, stream>>>(Wq, Wk, Wv, Wb);
  qkv_proj<<<512, 256, 0, stream>>>(x, Wb, bq, bk, bv, Qh, Kh, Vt);
  attn<<<256, 1024, 0, stream>>>(Qh, Kh, Vt, out);
}